// Round 1
// 710.176 us; speedup vs baseline: 1.0083x; 1.0083x over previous
//
#include <hip/hip_runtime.h>
#include <stdint.h>

// StaticQuantLinear: y = (clip(round(x/act_scale)) @ unpack_int4(W)^T) * (act_scale*wscale) + bias
// M=32, IN=8192, OUT=32768. weight_packed: [32768][4096] int32, low byte = 2 nibbles.
// 512 MiB weight stream -> memory-bound, gemm roofline ~83 us (cold HBM).
//
// R5 (this round): fuse the K-split reduction into the gemm. Previously:
//   gemm -> partial[4][32][32768] (16 MiB w) ; reduce reads 16 MiB + writes out.
// Now each block owns 16 output cols; its 4 waves split K (2048 each), reduce
// through LDS, and wave 0 applies scale+bias and writes out directly.
// Saves ~32 MiB HBM traffic + one kernel launch; ws use drops to 256 KiB (xq).
// Integer partials reassociate exactly -> bitwise-equal epilogue math.

#define M_DIM  32
#define IN_FEAT 8192
#define OUT_FEAT 32768
#define KSLICE (IN_FEAT / 4)        // 2048 per wave (4 waves split K)
#define NITER  (KSLICE / 64)        // 32 iterations of K=64 per wave

typedef __attribute__((ext_vector_type(4))) int   i32x4;
typedef __attribute__((ext_vector_type(4))) float f32x4;

// ---- quantize x -> int8, permuted layout ----------------------------------
// Within each 64-k block of a row, 8-k group g lands at byte offset:
//   g<4 ? g*16 : (g-4)*16+8
// so that lane krow's single 16B load at offset krow*16 holds k =
// {base+krow*8..+8} ++ {base+32+krow*8..+8}, matching the B-frag k order.
__global__ __launch_bounds__(256) void quant_kernel(
    const float* __restrict__ x,
    const float* __restrict__ act_scale,
    char* __restrict__ xq) {            // [32][8192] int8, permuted per 64-block
  const int t  = blockIdx.x * blockDim.x + threadIdx.x;   // 0..32767, 8 k each
  const int m  = t >> 10;              // IN/8 = 1024 groups per row
  const int g8 = t & 1023;
  const int k0 = g8 << 3;
  const int blk = k0 >> 6;
  const int g   = (k0 >> 3) & 7;
  const int pos = blk * 64 + ((g < 4) ? g * 16 : (g - 4) * 16 + 8);

  const float s = act_scale[0];
  const f32x4 v0 = *(const f32x4*)(x + (size_t)m * IN_FEAT + k0);
  const f32x4 v1 = *(const f32x4*)(x + (size_t)m * IN_FEAT + k0 + 4);
  int r0 = 0, r1 = 0;
#pragma unroll
  for (int j = 0; j < 4; ++j) {
    float qa = fminf(fmaxf(rintf(v0[j] / s), -127.0f), 127.0f);  // RNE == jnp.round
    float qb = fminf(fmaxf(rintf(v1[j] / s), -127.0f), 127.0f);
    r0 |= ((int)qa & 0xFF) << (8 * j);
    r1 |= ((int)qb & 0xFF) << (8 * j);
  }
  int* dst = (int*)(xq + (size_t)m * IN_FEAT + pos);   // 8-byte aligned
  dst[0] = r0;
  dst[1] = r1;
}

// ---- fused int8 GEMM + K-reduce + dequant epilogue ------------------------
// Block: 16 output cols (n = blockIdx.x*16 + l15). 4 waves split K into
// 2048-wide slices. Per wave: 32 rows (m) x 16 cols, K=64 per iter via
// mfma_i32_16x16x64_i8. Cross-wave reduce through LDS, wave 0 writes out.
// B: lane(l15,krow) loads bp[i*8+krow] (k = 64i+8krow..+8) and bp[i*8+4+krow]
// (k = 64i+32+8krow..+8). Per instruction, each row's 4 krow lanes cover one
// contiguous 64B line. A (permuted xq) provides identical k order.
__global__ __launch_bounds__(256) void gemm_kernel(
    const char*  __restrict__ xq,       // [32][8192] int8 (permuted blocks)
    const int*   __restrict__ wp,       // [32768][4096] int32 (low byte = 2 nibbles)
    const float* __restrict__ wscale,   // [32768]
    const float* __restrict__ act_scale,
    const float* __restrict__ bias,     // [32768]
    float* __restrict__ out)            // [32][32768]
{
  const int lane = threadIdx.x & 63;
  const int wave = threadIdx.x >> 6;    // K-slice index 0..3
  const int l15  = lane & 15;
  const int krow = lane >> 4;           // 0..3

  const int n     = (blockIdx.x << 4) + l15;
  const int kbase = wave * KSLICE;

  const i32x4* a0p = (const i32x4*)(xq + (size_t)l15        * IN_FEAT + kbase);
  const i32x4* a1p = (const i32x4*)(xq + (size_t)(l15 + 16) * IN_FEAT + kbase);
  const i32x4* bp  = (const i32x4*)((const char*)(wp + (size_t)n * (IN_FEAT / 2))
                                    + (size_t)kbase * 2);

  i32x4 acc0 = {0, 0, 0, 0};
  i32x4 acc1 = {0, 0, 0, 0};

  // prefetch iter 0
  i32x4 w_lo = __builtin_nontemporal_load(&bp[krow]);
  i32x4 w_hi = __builtin_nontemporal_load(&bp[4 + krow]);
  i32x4 a0   = a0p[krow];
  i32x4 a1   = a1p[krow];

#pragma unroll 2
  for (int i = 0; i < NITER; ++i) {
    const int ip = (i + 1 < NITER) ? (i + 1) : (NITER - 1);  // clamped (in-bounds)
    i32x4 w_lo_n = __builtin_nontemporal_load(&bp[ip * 8 + krow]);
    i32x4 w_hi_n = __builtin_nontemporal_load(&bp[ip * 8 + 4 + krow]);
    i32x4 a0_n   = a0p[ip * 4 + krow];
    i32x4 a1_n   = a1p[ip * 4 + krow];

    // pack 4 zero-extended low bytes -> 1 reg, isolate nibbles (<<4), interleave.
    // byte j of b covers k pair (2j, 2j+1): low nibble = even k, high = odd k.
    int b0  = w_lo[0] | (w_lo[1] << 8) | (w_lo[2] << 16) | (w_lo[3] << 24);
    int b1  = w_hi[0] | (w_hi[1] << 8) | (w_hi[2] << 16) | (w_hi[3] << 24);
    int lo0 = (b0 << 4) & 0xF0F0F0F0;   // (w<<4) for even k
    int hi0 =  b0       & 0xF0F0F0F0;   // (w<<4) for odd k
    int lo1 = (b1 << 4) & 0xF0F0F0F0;
    int hi1 =  b1       & 0xF0F0F0F0;
    i32x4 bfrag;
    bfrag[0] = __builtin_amdgcn_perm(hi0, lo0, 0x05010400);  // [L0,H0,L1,H1]
    bfrag[1] = __builtin_amdgcn_perm(hi0, lo0, 0x07030602);  // [L2,H2,L3,H3]
    bfrag[2] = __builtin_amdgcn_perm(hi1, lo1, 0x05010400);
    bfrag[3] = __builtin_amdgcn_perm(hi1, lo1, 0x07030602);

    acc0 = __builtin_amdgcn_mfma_i32_16x16x64_i8(a0, bfrag, acc0, 0, 0, 0);
    acc1 = __builtin_amdgcn_mfma_i32_16x16x64_i8(a1, bfrag, acc1, 0, 0, 0);

    w_lo = w_lo_n; w_hi = w_hi_n; a0 = a0_n; a1 = a1_n;
  }

  // C/D layout (shape-determined): col = lane&15, row = krow*4 + reg (acc1: +16)
  // Cross-wave K-reduce through LDS. Pad inner dim to 9 ints: lane stride 9 is
  // coprime with 32 banks -> conflict-free wave-0 reads.
  __shared__ int red[4][64][9];
#pragma unroll
  for (int r = 0; r < 4; ++r) {
    red[wave][lane][r]     = acc0[r];
    red[wave][lane][r + 4] = acc1[r];
  }
  __syncthreads();

  if (wave == 0) {
    const float as = act_scale[0] * (1.0f / 16.0f);   // undo w<<4
    const float sc = as * wscale[n];
    const float bs = bias[n];
    const int m0 = krow * 4;
#pragma unroll
    for (int r = 0; r < 4; ++r) {
      int s0 = red[0][lane][r]     + red[1][lane][r]
             + red[2][lane][r]     + red[3][lane][r];
      int s1 = red[0][lane][r + 4] + red[1][lane][r + 4]
             + red[2][lane][r + 4] + red[3][lane][r + 4];
      out[(size_t)(m0 + r)      * OUT_FEAT + n] = (float)s0 * sc + bs;
      out[(size_t)(m0 + r + 16) * OUT_FEAT + n] = (float)s1 * sc + bs;
    }
  }
}

extern "C" void kernel_launch(void* const* d_in, const int* in_sizes, int n_in,
                              void* d_out, int out_size, void* d_ws, size_t ws_size,
                              hipStream_t stream) {
  const float* x      = (const float*)d_in[0];
  const int*   wp     = (const int*)  d_in[1];
  const float* wscale = (const float*)d_in[2];
  const float* ascale = (const float*)d_in[3];
  const float* bias   = (const float*)d_in[4];
  float* out = (float*)d_out;

  char* xq = (char*)d_ws;                                   // 256 KiB

  quant_kernel<<<(M_DIM * IN_FEAT / 8) / 256, 256, 0, stream>>>(x, ascale, xq);
  gemm_kernel<<<OUT_FEAT / 16, 256, 0, stream>>>(xq, wp, wscale, ascale, bias, out);
}